// Round 1
// baseline (152.798 us; speedup 1.0000x reference)
//
#include <hip/hip_runtime.h>
#include <cstddef>

#define NN 3072
#define RR 16

// Prologue: key[i] = (cls not in {24,25,26}) ? batch[i] : -1
__global__ void frd_key_kernel(const int* __restrict__ cls,
                               const int* __restrict__ batch,
                               int* __restrict__ key) {
    int i = blockIdx.x * blockDim.x + threadIdx.x;
    if (i < NN) {
        int c = cls[i];
        bool valid = (c != 24) && (c != 25) && (c != 26);
        key[i] = valid ? batch[i] : -1;
    }
}

// Main: one thread per float4 quad of the output [N, N, R].
// idx in [0, N*N*4): pair = idx>>2, q = idx&3.
// out[pair*16 + q*4 .. +3] = pair_cond ? z1[i, q*4..]*z2[j, q*4..] : onehot0
__global__ __launch_bounds__(256)
void frd_main_kernel(const float* __restrict__ z1,
                     const float* __restrict__ z2,
                     const float* __restrict__ seg,
                     const int* __restrict__ key,
                     float* __restrict__ out) {
    const int total = NN * NN * 4;  // 37,748,736 < 2^31
    int idx = blockIdx.x * blockDim.x + threadIdx.x;
    const int stride = gridDim.x * blockDim.x;
    for (; idx < total; idx += stride) {
        const int pair = idx >> 2;
        const int q = idx & 3;
        const int i = pair / NN;          // magic-mul by compiler
        const int j = pair - i * NN;

        const float s = seg[pair];        // seg index == i*N + j == pair
        const int ki = key[i];
        const int kj = key[j];
        // seg_eff = seg_matrix + eye; pair iff seg_eff == 0 and keys match, valid
        const float seg_eff = s + ((i == j) ? 1.0f : 0.0f);
        const bool is_pair = (ki == kj) && (ki >= 0) && (seg_eff == 0.0f);

        // Unconditional loads — z1/z2 are 192 KB each, L2-resident.
        const float4 a = *reinterpret_cast<const float4*>(z1 + i * RR + q * 4);
        const float4 b = *reinterpret_cast<const float4*>(z2 + j * RR + q * 4);

        float4 r;
        const float d0 = (q == 0) ? 1.0f : 0.0f;  // one_hot(0, R) head
        r.x = is_pair ? a.x * b.x : d0;
        r.y = is_pair ? a.y * b.y : 0.0f;
        r.z = is_pair ? a.z * b.z : 0.0f;
        r.w = is_pair ? a.w * b.w : 0.0f;

        *reinterpret_cast<float4*>(out + (size_t)idx * 4) = r;
    }
}

extern "C" void kernel_launch(void* const* d_in, const int* in_sizes, int n_in,
                              void* d_out, int out_size, void* d_ws, size_t ws_size,
                              hipStream_t stream) {
    const float* z1  = (const float*)d_in[0];
    const float* z2  = (const float*)d_in[1];
    const float* seg = (const float*)d_in[2];
    const int* cls   = (const int*)d_in[3];
    const int* batch = (const int*)d_in[4];
    float* out = (float*)d_out;
    int* key = (int*)d_ws;

    frd_key_kernel<<<(NN + 255) / 256, 256, 0, stream>>>(cls, batch, key);

    const int total = NN * NN * 4;
    int blocks = 2048;                     // 256 CU × 8 blocks, grid-stride
    frd_main_kernel<<<blocks, 256, 0, stream>>>(z1, z2, seg, key, out);
}

// Round 2
// 146.899 us; speedup vs baseline: 1.0402x; 1.0402x over previous
//
#include <hip/hip_runtime.h>
#include <cstddef>

#define NN 3072
#define RR 16

typedef float f32x4 __attribute__((ext_vector_type(4)));

// Prologue: key[i] = (cls not in {24,25,26}) ? batch[i] : -1
__global__ void frd_key_kernel(const int* __restrict__ cls,
                               const int* __restrict__ batch,
                               int* __restrict__ key) {
    int i = blockIdx.x * blockDim.x + threadIdx.x;
    if (i < NN) {
        int c = cls[i];
        bool valid = (c != 24) && (c != 25) && (c != 26);
        key[i] = valid ? batch[i] : -1;
    }
}

// Main: one thread per float4 quad of the output [N, N, R]; exact grid, no loop.
// idx in [0, N*N*4): pair = idx>>2, q = idx&3.
// out[idx*4 .. idx*4+3] = pair_cond ? z1[i, q*4..]*z2[j, q*4..] : onehot0
__global__ __launch_bounds__(256)
void frd_main_kernel(const float* __restrict__ z1,
                     const float* __restrict__ z2,
                     const float* __restrict__ seg,
                     const int* __restrict__ key,
                     float* __restrict__ out) {
    const int idx = blockIdx.x * blockDim.x + threadIdx.x;  // grid sized exactly
    const int pair = idx >> 2;
    const int q = idx & 3;
    const int i = pair / NN;          // magic-mul by compiler
    const int j = pair - i * NN;

    // seg index == i*N + j == pair; read-once stream -> nontemporal
    const float s = __builtin_nontemporal_load(seg + pair);
    const int ki = key[i];
    const int kj = key[j];
    // seg_eff = seg_matrix + eye; pair iff seg_eff == 0, keys match, both valid
    const float seg_eff = s + ((i == j) ? 1.0f : 0.0f);
    const bool is_pair = (ki == kj) && (ki >= 0) && (seg_eff == 0.0f);

    // Unconditional loads — z1/z2 are 192 KB each, cache-resident.
    const float4 a = *reinterpret_cast<const float4*>(z1 + i * RR + q * 4);
    const float4 b = *reinterpret_cast<const float4*>(z2 + j * RR + q * 4);

    f32x4 r;
    const float d0 = (q == 0) ? 1.0f : 0.0f;  // one_hot(0, R) head
    r.x = is_pair ? a.x * b.x : d0;
    r.y = is_pair ? a.y * b.y : 0.0f;
    r.z = is_pair ? a.z * b.z : 0.0f;
    r.w = is_pair ? a.w * b.w : 0.0f;

    // Streaming write (604 MB, no reuse) -> nontemporal full-line stores
    __builtin_nontemporal_store(r, reinterpret_cast<f32x4*>(out + (size_t)idx * 4));
}

extern "C" void kernel_launch(void* const* d_in, const int* in_sizes, int n_in,
                              void* d_out, int out_size, void* d_ws, size_t ws_size,
                              hipStream_t stream) {
    const float* z1  = (const float*)d_in[0];
    const float* z2  = (const float*)d_in[1];
    const float* seg = (const float*)d_in[2];
    const int* cls   = (const int*)d_in[3];
    const int* batch = (const int*)d_in[4];
    float* out = (float*)d_out;
    int* key = (int*)d_ws;

    frd_key_kernel<<<(NN + 255) / 256, 256, 0, stream>>>(cls, batch, key);

    const int total = NN * NN * 4;          // 37,748,736 = 147,456 * 256 exactly
    frd_main_kernel<<<total / 256, 256, 0, stream>>>(z1, z2, seg, key, out);
}

// Round 3
// 126.621 us; speedup vs baseline: 1.2067x; 1.1602x over previous
//
#include <hip/hip_runtime.h>
#include <cstddef>

#define NN 3072
#define RR 16
#define UNROLL 8

typedef float f32x4 __attribute__((ext_vector_type(4)));

// Prologue: key[i] = (cls not in {24,25,26}) ? batch[i] : -1
__global__ void frd_key_kernel(const int* __restrict__ cls,
                               const int* __restrict__ batch,
                               int* __restrict__ key) {
    int i = blockIdx.x * blockDim.x + threadIdx.x;
    if (i < NN) {
        int c = cls[i];
        bool valid = (c != 24) && (c != 25) && (c != 26);
        key[i] = valid ? batch[i] : -1;
    }
}

// Main: each thread handles UNROLL independent float4 quads of out [N, N, R].
// Block covers 256*UNROLL contiguous quads (32 KB); iteration k covers a
// 4 KB contiguous slab -> every store is a full 1 KB/wave coalesced burst.
__global__ __launch_bounds__(256)
void frd_main_kernel(const float* __restrict__ z1,
                     const float* __restrict__ z2,
                     const float* __restrict__ seg,
                     const int* __restrict__ key,
                     float* __restrict__ out) {
    const int base = blockIdx.x * (256 * UNROLL) + threadIdx.x;
    const float d0 = ((threadIdx.x & 3) == 0) ? 1.0f : 0.0f;  // one_hot(0,R) head

#pragma unroll
    for (int k = 0; k < UNROLL; ++k) {
        const int idx = base + k * 256;
        const int pair = idx >> 2;
        const int q = idx & 3;
        const int i = pair / NN;          // magic-mul by compiler
        const int j = pair - i * NN;

        // seg index == i*N + j == pair; read-once stream
        const float s = __builtin_nontemporal_load(seg + pair);
        const int ki = key[i];
        const int kj = key[j];
        // seg_eff = seg_matrix + eye; pair iff seg_eff == 0, keys match, valid
        const float seg_eff = s + ((i == j) ? 1.0f : 0.0f);
        const bool is_pair = (ki == kj) && (ki >= 0) && (seg_eff == 0.0f);

        // Unconditional loads — z1/z2 are 192 KB each, cache-resident.
        const float4 a = *reinterpret_cast<const float4*>(z1 + i * RR + q * 4);
        const float4 b = *reinterpret_cast<const float4*>(z2 + j * RR + q * 4);

        f32x4 r;
        r.x = is_pair ? a.x * b.x : d0;
        r.y = is_pair ? a.y * b.y : 0.0f;
        r.z = is_pair ? a.z * b.z : 0.0f;
        r.w = is_pair ? a.w * b.w : 0.0f;

        // Streaming write (604 MB, no reuse)
        __builtin_nontemporal_store(r, reinterpret_cast<f32x4*>(out + (size_t)idx * 4));
    }
}

extern "C" void kernel_launch(void* const* d_in, const int* in_sizes, int n_in,
                              void* d_out, int out_size, void* d_ws, size_t ws_size,
                              hipStream_t stream) {
    const float* z1  = (const float*)d_in[0];
    const float* z2  = (const float*)d_in[1];
    const float* seg = (const float*)d_in[2];
    const int* cls   = (const int*)d_in[3];
    const int* batch = (const int*)d_in[4];
    float* out = (float*)d_out;
    int* key = (int*)d_ws;

    frd_key_kernel<<<(NN + 255) / 256, 256, 0, stream>>>(cls, batch, key);

    const int total = NN * NN * 4;          // 37,748,736 = 18,432 * 256 * 8 exactly
    frd_main_kernel<<<total / (256 * UNROLL), 256, 0, stream>>>(z1, z2, seg, key, out);
}